// Round 1
// baseline (78.424 us; speedup 1.0000x reference)
//
#include <hip/hip_runtime.h>
#include <math.h>

#define H 1024
#define E 1024
#define V 50257
#define L 64
#define HE 2048

__device__ inline float wave_reduce_sum(float v) {
    #pragma unroll
    for (int off = 32; off > 0; off >>= 1)
        v += __shfl_down(v, off, 64);
    return v;
}

// ---- Kernel A: attn_logits[b] = dot(concat(embedded, h0), attn_w[b]) + attn_b[b]
__global__ void k_attn_logits(const int* __restrict__ inp,
                              const float* __restrict__ hidden,
                              const float* __restrict__ emb,
                              const float* __restrict__ attn_w,
                              const float* __restrict__ attn_b,
                              float* __restrict__ logits) {
    int b = blockIdx.x;          // 0..63
    int t = threadIdx.x;         // 0..255
    const float* erow = emb + (size_t)inp[0] * E;
    const float4* w  = (const float4*)(attn_w + (size_t)b * HE);
    const float4* e4 = (const float4*)erow;
    const float4* h4 = (const float4*)hidden;
    float4 w1 = w[t];
    float4 ev = e4[t];
    float4 w2 = w[256 + t];
    float4 hv = h4[t];
    float s = w1.x*ev.x + w1.y*ev.y + w1.z*ev.z + w1.w*ev.w
            + w2.x*hv.x + w2.y*hv.y + w2.z*hv.z + w2.w*hv.w;
    s = wave_reduce_sum(s);
    __shared__ float red[4];
    if ((t & 63) == 0) red[t >> 6] = s;
    __syncthreads();
    if (t == 0)
        logits[b] = red[0] + red[1] + red[2] + red[3] + attn_b[b];
}

// ---- Kernel B: softmax(64) + attn_applied[j] = sum_l w[l]*enc[l][j]; writes attn_weights
__global__ void k_attn_apply(const float* __restrict__ logits,
                             const float* __restrict__ enc,
                             float* __restrict__ attn_applied,
                             float* __restrict__ out_weights) {
    __shared__ float wsm[L];
    int t = threadIdx.x;
    if (t < 64) {
        float v = logits[t];
        float m = v;
        #pragma unroll
        for (int off = 32; off > 0; off >>= 1) m = fmaxf(m, __shfl_xor(m, off, 64));
        float ex = expf(v - m);
        float s = ex;
        #pragma unroll
        for (int off = 32; off > 0; off >>= 1) s += __shfl_xor(s, off, 64);
        wsm[t] = ex / s;
    }
    __syncthreads();
    int j = blockIdx.x * blockDim.x + t;   // grid 4 x 256 -> 0..1023
    float acc = 0.f;
    #pragma unroll 8
    for (int l = 0; l < L; ++l)
        acc += wsm[l] * enc[l * H + j];
    attn_applied[j] = acc;
    if (blockIdx.x == 0 && t < L) out_weights[t] = wsm[t];
}

// ---- Kernel C: x = relu(concat(embedded, attn_applied) @ comb_w.T + comb_b); wave per row
__global__ void k_comb(const int* __restrict__ inp,
                       const float* __restrict__ emb,
                       const float* __restrict__ attn_applied,
                       const float* __restrict__ comb_w,
                       const float* __restrict__ comb_b,
                       float* __restrict__ x) {
    int wid  = (blockIdx.x * blockDim.x + threadIdx.x) >> 6;  // row 0..1023
    int lane = threadIdx.x & 63;
    const float* erow = emb + (size_t)inp[0] * E;
    const float4* w  = (const float4*)(comb_w + (size_t)wid * HE);
    const float4* e4 = (const float4*)erow;
    const float4* a4 = (const float4*)attn_applied;
    float s = 0.f;
    #pragma unroll
    for (int i = 0; i < 4; ++i) {
        float4 wv = w[i * 64 + lane];
        float4 ev = e4[i * 64 + lane];
        s += wv.x*ev.x + wv.y*ev.y + wv.z*ev.z + wv.w*ev.w;
    }
    #pragma unroll
    for (int i = 0; i < 4; ++i) {
        float4 wv = w[256 + i * 64 + lane];
        float4 av = a4[i * 64 + lane];
        s += wv.x*av.x + wv.y*av.y + wv.z*av.z + wv.w*av.w;
    }
    s = wave_reduce_sum(s);
    if (lane == 0) x[wid] = fmaxf(s + comb_b[wid], 0.f);
}

// ---- Kernel D: GRU cell, wave per output j (6 dots of 1024)
__global__ void k_gru(const float* __restrict__ x,
                      const float* __restrict__ hidden,
                      const float* __restrict__ w_ih,
                      const float* __restrict__ b_ih,
                      const float* __restrict__ w_hh,
                      const float* __restrict__ b_hh,
                      float* __restrict__ h_new) {
    int wid  = (blockIdx.x * blockDim.x + threadIdx.x) >> 6;  // j 0..1023
    int lane = threadIdx.x & 63;
    const float4* x4 = (const float4*)x;
    const float4* h4 = (const float4*)hidden;
    float4 xv[4], hv[4];
    #pragma unroll
    for (int i = 0; i < 4; ++i) { xv[i] = x4[i * 64 + lane]; hv[i] = h4[i * 64 + lane]; }
    float acc[6] = {0.f, 0.f, 0.f, 0.f, 0.f, 0.f};
    #pragma unroll
    for (int g = 0; g < 3; ++g) {
        const float4* wi = (const float4*)(w_ih + (size_t)(g * H + wid) * E);
        const float4* wh = (const float4*)(w_hh + (size_t)(g * H + wid) * H);
        #pragma unroll
        for (int i = 0; i < 4; ++i) {
            float4 a = wi[i * 64 + lane];
            acc[g]     += a.x*xv[i].x + a.y*xv[i].y + a.z*xv[i].z + a.w*xv[i].w;
            float4 b = wh[i * 64 + lane];
            acc[3 + g] += b.x*hv[i].x + b.y*hv[i].y + b.z*hv[i].z + b.w*hv[i].w;
        }
    }
    #pragma unroll
    for (int g = 0; g < 6; ++g) acc[g] = wave_reduce_sum(acc[g]);
    if (lane == 0) {
        float i_r = acc[0] + b_ih[wid];
        float i_z = acc[1] + b_ih[H + wid];
        float i_n = acc[2] + b_ih[2 * H + wid];
        float h_r = acc[3] + b_hh[wid];
        float h_z = acc[4] + b_hh[H + wid];
        float h_n = acc[5] + b_hh[2 * H + wid];
        float r = 1.f / (1.f + expf(-(i_r + h_r)));
        float z = 1.f / (1.f + expf(-(i_z + h_z)));
        float n = tanhf(i_n + r * h_n);
        h_new[wid] = (1.f - z) * n + z * hidden[wid];
    }
}

// ---- Kernel E: logits[v] = dot(h_new, out_w[v]) + out_b[v]; per-block (max,sumexp) partials
__global__ void k_outproj(const float* __restrict__ h_new,
                          const float* __restrict__ out_w,
                          const float* __restrict__ out_b,
                          float* __restrict__ logits,
                          float2* __restrict__ partials) {
    int wid  = threadIdx.x >> 6;         // 0..3
    int lane = threadIdx.x & 63;
    int row  = blockIdx.x * 4 + wid;
    __shared__ float sm[4], ss[4];
    if (row < V) {
        const float4* w  = (const float4*)(out_w + (size_t)row * H);
        const float4* h4 = (const float4*)h_new;
        float s = 0.f;
        #pragma unroll
        for (int i = 0; i < 4; ++i) {
            float4 wv = w[i * 64 + lane];
            float4 hv = h4[i * 64 + lane];
            s += wv.x*hv.x + wv.y*hv.y + wv.z*hv.z + wv.w*hv.w;
        }
        s = wave_reduce_sum(s);
        if (lane == 0) {
            s += out_b[row];
            logits[row] = s;
            sm[wid] = s; ss[wid] = 1.f;
        }
    } else if (lane == 0) {
        sm[wid] = -INFINITY; ss[wid] = 0.f;
    }
    __syncthreads();
    if (threadIdx.x == 0) {
        float M = fmaxf(fmaxf(sm[0], sm[1]), fmaxf(sm[2], sm[3]));
        float S = 0.f;
        #pragma unroll
        for (int i = 0; i < 4; ++i)
            if (ss[i] > 0.f) S += ss[i] * expf(sm[i] - M);
        partials[blockIdx.x] = make_float2(M, S);
    }
}

__device__ inline void ms_merge(float& M, float& S, float m2, float s2) {
    if (s2 > 0.f) {
        if (m2 > M) { S = S * expf(M - m2) + s2; M = m2; }
        else        { S += s2 * expf(m2 - M); }
    }
}

// ---- Kernel F: reduce per-block partials -> logZ = M + log(S)
__global__ void k_reduce_ms(const float2* __restrict__ partials, int nb,
                            float* __restrict__ MS) {
    int t = threadIdx.x;
    float M = -INFINITY, S = 0.f;
    for (int i = t; i < nb; i += 256) {
        float2 p = partials[i];
        ms_merge(M, S, p.x, p.y);
    }
    #pragma unroll
    for (int off = 32; off > 0; off >>= 1) {
        float m2 = __shfl_down(M, off, 64);
        float s2 = __shfl_down(S, off, 64);
        ms_merge(M, S, m2, s2);
    }
    __shared__ float sm[4], ss[4];
    if ((t & 63) == 0) { sm[t >> 6] = M; ss[t >> 6] = S; }
    __syncthreads();
    if (t == 0) {
        #pragma unroll
        for (int i = 1; i < 4; ++i) ms_merge(sm[0], ss[0], sm[i], ss[i]);
        MS[0] = sm[0] + logf(ss[0]);
    }
}

// ---- Kernel G: logp[v] = logits[v] - logZ  (in place in d_out)
__global__ void k_logsoftmax(float* __restrict__ logp,
                             const float* __restrict__ MS) {
    int i = blockIdx.x * blockDim.x + threadIdx.x;
    if (i < V) logp[i] -= MS[0];
}

extern "C" void kernel_launch(void* const* d_in, const int* in_sizes, int n_in,
                              void* d_out, int out_size, void* d_ws, size_t ws_size,
                              hipStream_t stream) {
    const int*   inp     = (const int*)d_in[0];
    const float* hidden  = (const float*)d_in[1];
    const float* enc     = (const float*)d_in[2];
    const float* emb     = (const float*)d_in[3];
    const float* attn_w  = (const float*)d_in[4];
    const float* attn_b  = (const float*)d_in[5];
    const float* comb_w  = (const float*)d_in[6];
    const float* comb_b  = (const float*)d_in[7];
    const float* w_ih    = (const float*)d_in[8];
    const float* b_ih    = (const float*)d_in[9];
    const float* w_hh    = (const float*)d_in[10];
    const float* b_hh    = (const float*)d_in[11];
    const float* out_w   = (const float*)d_in[12];
    const float* out_b   = (const float*)d_in[13];

    float* out          = (float*)d_out;
    float* logp         = out;              // V
    float* h_new        = out + V;          // H
    float* attn_weights = out + V + H;      // L

    float* ws           = (float*)d_ws;
    float* attn_logits  = ws;               // 64
    float* attn_applied = ws + 64;          // 1024
    float* x            = ws + 64 + 1024;   // 1024
    int nb = (V + 3) / 4;                   // 12565 blocks for kernel E
    float2* partials    = (float2*)(ws + 2112);      // 8B-aligned (2112 floats)
    float*  MS          = (float*)(partials + nb);

    k_attn_logits<<<64, 256, 0, stream>>>(inp, hidden, emb, attn_w, attn_b, attn_logits);
    k_attn_apply<<<4, 256, 0, stream>>>(attn_logits, enc, attn_applied, attn_weights);
    k_comb<<<256, 256, 0, stream>>>(inp, emb, attn_applied, comb_w, comb_b, x);
    k_gru<<<256, 256, 0, stream>>>(x, hidden, w_ih, b_ih, w_hh, b_hh, h_new);
    k_outproj<<<nb, 256, 0, stream>>>(h_new, out_w, out_b, logp, partials);
    k_reduce_ms<<<1, 256, 0, stream>>>(partials, nb, MS);
    k_logsoftmax<<<(V + 255) / 256, 256, 0, stream>>>(logp, MS);
}

// Round 2
// 75.459 us; speedup vs baseline: 1.0393x; 1.0393x over previous
//
#include <hip/hip_runtime.h>
#include <math.h>

#define H 1024
#define E 1024
#define V 50257
#define L 64
#define HE 2048

__device__ inline float wave_reduce_sum(float v) {
    #pragma unroll
    for (int off = 32; off > 0; off >>= 1)
        v += __shfl_down(v, off, 64);
    return v;
}

__device__ inline float wave_allreduce_sum(float v) {
    #pragma unroll
    for (int off = 32; off > 0; off >>= 1)
        v += __shfl_xor(v, off, 64);
    return v;
}

__device__ inline void ms_merge(float& M, float& S, float m2, float s2) {
    if (s2 > 0.f) {
        if (m2 > M) { S = S * expf(M - m2) + s2; M = m2; }
        else        { S += s2 * expf(m2 - M); }
    }
}

// ---- Kernel 1 (fused A+B): attn logits -> softmax -> attn_applied, one block of 1024
__global__ __launch_bounds__(1024) void k_attn_fused(
        const int* __restrict__ inp,
        const float* __restrict__ hidden,
        const float* __restrict__ emb,
        const float* __restrict__ attn_w,
        const float* __restrict__ attn_b,
        const float* __restrict__ enc,
        float* __restrict__ attn_applied,
        float* __restrict__ out_weights) {
    __shared__ float lg[L];
    __shared__ float wsm[L];
    int t = threadIdx.x;
    int wave = t >> 6, lane = t & 63;
    const float* erow = emb + (size_t)inp[0] * E;
    const float4* e4 = (const float4*)erow;
    const float4* h4 = (const float4*)hidden;
    // phase 1: 16 waves x 4 rows of attn_w (each row a 2048-dot)
    #pragma unroll
    for (int r = wave; r < L; r += 16) {
        const float4* w = (const float4*)(attn_w + (size_t)r * HE);
        float s = 0.f;
        #pragma unroll
        for (int i = 0; i < 4; ++i) {
            float4 wv = w[i * 64 + lane];
            float4 ev = e4[i * 64 + lane];
            s += wv.x*ev.x + wv.y*ev.y + wv.z*ev.z + wv.w*ev.w;
        }
        #pragma unroll
        for (int i = 0; i < 4; ++i) {
            float4 wv = w[256 + i * 64 + lane];
            float4 hv = h4[i * 64 + lane];
            s += wv.x*hv.x + wv.y*hv.y + wv.z*hv.z + wv.w*hv.w;
        }
        s = wave_reduce_sum(s);
        if (lane == 0) lg[r] = s + attn_b[r];
    }
    __syncthreads();
    // phase 2: softmax over 64 (wave 0 only, t<64)
    if (t < 64) {
        float v = lg[t];
        float m = v;
        #pragma unroll
        for (int off = 32; off > 0; off >>= 1) m = fmaxf(m, __shfl_xor(m, off, 64));
        float ex = expf(v - m);
        float ssum = ex;
        #pragma unroll
        for (int off = 32; off > 0; off >>= 1) ssum += __shfl_xor(ssum, off, 64);
        float w = ex / ssum;
        wsm[t] = w;
        out_weights[t] = w;
    }
    __syncthreads();
    // phase 3: attn_applied[t] = sum_l wsm[l]*enc[l][t]
    float acc = 0.f;
    #pragma unroll 16
    for (int l = 0; l < L; ++l)
        acc += wsm[l] * enc[l * H + t];
    attn_applied[t] = acc;
}

// ---- Kernel 2: comb + relu. Block 256 = 4 waves = 2 outputs, 2-wave split-K.
__global__ __launch_bounds__(256) void k_comb(
        const int* __restrict__ inp,
        const float* __restrict__ emb,
        const float* __restrict__ attn_applied,
        const float* __restrict__ comb_w,
        const float* __restrict__ comb_b,
        float* __restrict__ x) {
    int t = threadIdx.x, wave = t >> 6, lane = t & 63;
    int row  = blockIdx.x * 2 + (wave >> 1);
    int half = wave & 1;
    const float* erow = emb + (size_t)inp[0] * E;
    const float4* vec = half ? (const float4*)attn_applied : (const float4*)erow;
    const float4* w = (const float4*)(comb_w + (size_t)row * HE + half * E);
    float s = 0.f;
    #pragma unroll
    for (int i = 0; i < 4; ++i) {
        float4 wv = w[i * 64 + lane];
        float4 vv = vec[i * 64 + lane];
        s += wv.x*vv.x + wv.y*vv.y + wv.z*vv.z + wv.w*vv.w;
    }
    s = wave_reduce_sum(s);
    __shared__ float red[4];
    if (lane == 0) red[wave] = s;
    __syncthreads();
    if (t < 2) {
        int r = blockIdx.x * 2 + t;
        x[r] = fmaxf(red[2 * t] + red[2 * t + 1] + comb_b[r], 0.f);
    }
}

// ---- Kernel 3: GRU. Block 384 = 6 waves, one output/block, one gate-dot per wave.
__global__ __launch_bounds__(384) void k_gru(
        const float* __restrict__ x,
        const float* __restrict__ hidden,
        const float* __restrict__ w_ih,
        const float* __restrict__ b_ih,
        const float* __restrict__ w_hh,
        const float* __restrict__ b_hh,
        float* __restrict__ h_new) {
    int t = threadIdx.x, wave = t >> 6, lane = t & 63;
    int j = blockIdx.x;
    const float* W    = (wave < 3) ? w_ih : w_hh;
    const float* vsrc = (wave < 3) ? x    : hidden;
    int g = (wave < 3) ? wave : wave - 3;
    const float4* wr = (const float4*)(W + (size_t)(g * H + j) * H);
    const float4* v4 = (const float4*)vsrc;
    float s = 0.f;
    #pragma unroll
    for (int i = 0; i < 4; ++i) {
        float4 wv = wr[i * 64 + lane];
        float4 vv = v4[i * 64 + lane];
        s += wv.x*vv.x + wv.y*vv.y + wv.z*vv.z + wv.w*vv.w;
    }
    s = wave_reduce_sum(s);
    __shared__ float red[6];
    if (lane == 0) red[wave] = s;
    __syncthreads();
    if (t == 0) {
        float i_r = red[0] + b_ih[j];
        float i_z = red[1] + b_ih[H + j];
        float i_n = red[2] + b_ih[2 * H + j];
        float h_r = red[3] + b_hh[j];
        float h_z = red[4] + b_hh[H + j];
        float h_n = red[5] + b_hh[2 * H + j];
        float r = 1.f / (1.f + expf(-(i_r + h_r)));
        float z = 1.f / (1.f + expf(-(i_z + h_z)));
        float n = tanhf(i_n + r * h_n);
        h_new[j] = (1.f - z) * n + z * hidden[j];
    }
}

// ---- Kernel 4: vocab matvec. Block 256 = 4 waves, 4 rows/wave (h in regs), 16 rows/block.
__global__ __launch_bounds__(256) void k_outproj(
        const float* __restrict__ h_new,
        const float* __restrict__ out_w,
        const float* __restrict__ out_b,
        float* __restrict__ logits,
        float2* __restrict__ partials) {
    int t = threadIdx.x, wave = t >> 6, lane = t & 63;
    int row0 = blockIdx.x * 16 + wave * 4;
    const float4* h4 = (const float4*)h_new;
    float4 hv[4];
    #pragma unroll
    for (int i = 0; i < 4; ++i) hv[i] = h4[i * 64 + lane];
    float M = -INFINITY, S = 0.f;
    #pragma unroll
    for (int rr = 0; rr < 4; ++rr) {
        int row = row0 + rr;
        if (row < V) {
            const float4* w = (const float4*)(out_w + (size_t)row * H);
            float s = 0.f;
            #pragma unroll
            for (int i = 0; i < 4; ++i) {
                float4 wv = w[i * 64 + lane];
                s += wv.x*hv[i].x + wv.y*hv[i].y + wv.z*hv[i].z + wv.w*hv[i].w;
            }
            s = wave_allreduce_sum(s);
            s += out_b[row];
            if (lane == 0) logits[row] = s;
            // online (max, sumexp) — identical on all lanes
            if (s > M) { S = S * expf(M - s) + 1.f; M = s; }
            else       { S += expf(s - M); }
        }
    }
    __shared__ float sm[4], ss[4];
    if (lane == 0) { sm[wave] = M; ss[wave] = S; }
    __syncthreads();
    if (t == 0) {
        #pragma unroll
        for (int i = 1; i < 4; ++i) ms_merge(sm[0], ss[0], sm[i], ss[i]);
        partials[blockIdx.x] = make_float2(sm[0], ss[0]);
    }
}

// ---- Kernel 5: per-block redundant (M,S) reduce from L2 + subtract logZ
__global__ __launch_bounds__(256) void k_logsoftmax(
        float* __restrict__ logp,
        const float2* __restrict__ partials, int nb) {
    int t = threadIdx.x;
    float M = -INFINITY, S = 0.f;
    for (int i = t; i < nb; i += 256) {
        float2 p = partials[i];
        ms_merge(M, S, p.x, p.y);
    }
    #pragma unroll
    for (int off = 32; off > 0; off >>= 1) {
        float m2 = __shfl_down(M, off, 64);
        float s2 = __shfl_down(S, off, 64);
        ms_merge(M, S, m2, s2);
    }
    __shared__ float sm[4], ss[4];
    __shared__ float lz;
    if ((t & 63) == 0) { sm[t >> 6] = M; ss[t >> 6] = S; }
    __syncthreads();
    if (t == 0) {
        #pragma unroll
        for (int i = 1; i < 4; ++i) ms_merge(sm[0], ss[0], sm[i], ss[i]);
        lz = sm[0] + logf(ss[0]);
    }
    __syncthreads();
    int i = blockIdx.x * 256 + t;
    if (i < V) logp[i] -= lz;
}

extern "C" void kernel_launch(void* const* d_in, const int* in_sizes, int n_in,
                              void* d_out, int out_size, void* d_ws, size_t ws_size,
                              hipStream_t stream) {
    const int*   inp     = (const int*)d_in[0];
    const float* hidden  = (const float*)d_in[1];
    const float* enc     = (const float*)d_in[2];
    const float* emb     = (const float*)d_in[3];
    const float* attn_w  = (const float*)d_in[4];
    const float* attn_b  = (const float*)d_in[5];
    const float* comb_w  = (const float*)d_in[6];
    const float* comb_b  = (const float*)d_in[7];
    const float* w_ih    = (const float*)d_in[8];
    const float* b_ih    = (const float*)d_in[9];
    const float* w_hh    = (const float*)d_in[10];
    const float* b_hh    = (const float*)d_in[11];
    const float* out_w   = (const float*)d_in[12];
    const float* out_b   = (const float*)d_in[13];

    float* out          = (float*)d_out;
    float* logp         = out;              // V
    float* h_new        = out + V;          // H
    float* attn_weights = out + V + H;      // L

    float* ws           = (float*)d_ws;
    float* attn_applied = ws;               // 1024
    float* x            = ws + 1024;        // 1024
    const int nb = (V + 15) / 16;           // 3142
    float2* partials    = (float2*)(ws + 2048);   // 8B aligned

    k_attn_fused<<<1, 1024, 0, stream>>>(inp, hidden, emb, attn_w, attn_b,
                                         enc, attn_applied, attn_weights);
    k_comb<<<512, 256, 0, stream>>>(inp, emb, attn_applied, comb_w, comb_b, x);
    k_gru<<<1024, 384, 0, stream>>>(x, hidden, w_ih, b_ih, w_hh, b_hh, h_new);
    k_outproj<<<nb, 256, 0, stream>>>(h_new, out_w, out_b, logp, partials);
    k_logsoftmax<<<(V + 255) / 256, 256, 0, stream>>>(logp, partials, nb);
}